// Round 10
// baseline (185.387 us; speedup 1.0000x reference)
//
#include <hip/hip_runtime.h>
#include <hip/hip_bf16.h>

typedef __bf16 bf16x8 __attribute__((ext_vector_type(8)));
typedef __bf16 bf16x4 __attribute__((ext_vector_type(4)));
typedef float f32x4 __attribute__((ext_vector_type(4)));

#define WORLD 8
#define M_DIM 8192
#define N_DIM 2048
#define KL 256
#define K_TOT 2048

#define BM 256
#define BN 256
#define BK 64
#define NT (K_TOT / BK)   // 32 K-tiles

#define AS1 __attribute__((address_space(1)))
#define AS3 __attribute__((address_space(3)))

#define BAR()    __builtin_amdgcn_s_barrier()
#define VMCNT0() asm volatile("s_waitcnt vmcnt(0)" ::: "memory")
#define PRIO1()  __builtin_amdgcn_s_setprio(1)
#define PRIO0()  __builtin_amdgcn_s_setprio(0)

// ---------------------------------------------------------------------------
// Pass 1: fp32 -> bf16 conversion + rank-dim gather (unchanged).
// ---------------------------------------------------------------------------
__global__ __launch_bounds__(256) void GemmRS_convert_kernel(
    const float* __restrict__ A,
    const float* __restrict__ W,
    __bf16* __restrict__ Abf,
    __bf16* __restrict__ Wbf)
{
    const long long GA = (long long)WORLD * M_DIM * KL / 4;
    const long long GW = (long long)WORLD * N_DIM * KL / 4;
    const long long stride = (long long)gridDim.x * blockDim.x;
    for (long long g = (long long)blockIdx.x * blockDim.x + threadIdx.x;
         g < GA + GW; g += stride) {
        if (g < GA) {
            const long long e = g * 4;
            const int k = (int)(e & (KL - 1));
            const int m = (int)((e >> 8) & (M_DIM - 1));
            const int r = (int)(e >> 21);
            const float4 v = *reinterpret_cast<const float4*>(A + e);
            bf16x4 o;
            o[0] = (__bf16)v.x; o[1] = (__bf16)v.y;
            o[2] = (__bf16)v.z; o[3] = (__bf16)v.w;
            *reinterpret_cast<bf16x4*>(Abf + (size_t)m * K_TOT + r * KL + k) = o;
        } else {
            const long long e = (g - GA) * 4;
            const int k = (int)(e & (KL - 1));
            const int n = (int)((e >> 8) & (N_DIM - 1));
            const int r = (int)(e >> 19);
            const float4 v = *reinterpret_cast<const float4*>(W + e);
            bf16x4 o;
            o[0] = (__bf16)v.x; o[1] = (__bf16)v.y;
            o[2] = (__bf16)v.z; o[3] = (__bf16)v.w;
            *reinterpret_cast<bf16x4*>(Wbf + (size_t)n * K_TOT + r * KL + k) = o;
        }
    }
}

// ---------------------------------------------------------------------------
// Pass 2 (R10): 256x256 tile, 8 waves x 128x64, BK=64.
// A-operand: DIRECT from global (L1/L2 path, no LDS round-trip, no swizzle).
// B-operand: gload_lds staged, swizzled, 2-buffer ring (64 KiB LDS).
// 3 phases per tile:
//   P0: ga A<0> (8) + ds b01 (4)            -> BAR -> mma<0,0> (16)
//   P1: ds b23 (4)                          -> BAR -> mma<0,1> (16)
//   P2: ga A<1> (8) + stage B(t+1) (4 gl)   -> BAR -> mma<1,1>+<1,0> (32)
//       -> VMCNT0 -> BAR (boundary)
// LDS traffic per K-128: 192 KiB (was 512 KiB) — if the LDS port is the
// binding resource, this is a ~2.7x cut of the dominant term.
// ---------------------------------------------------------------------------

__device__ __forceinline__ void stage_half(const __bf16* srcbase, __bf16* dstbase,
                                           int lane, int wave) {
    const int rl = lane >> 3;
    const int g  = (lane & 7) ^ rl;           // swizzle on GLOBAL source
    const __bf16* s = srcbase + (size_t)(wave * 8 + rl) * K_TOT + g * 8;
#pragma unroll
    for (int j = 0; j < 2; ++j) {
        __builtin_amdgcn_global_load_lds(
            (const AS1 void*)(s + (size_t)(j * 64) * K_TOT),
            (AS3 void*)(dstbase + (j * 64 + wave * 8) * BK),
            16, 0, 0);
    }
}

// A fragments straight from global: lane reads 16 contiguous bytes.
template<int MH>
__device__ __forceinline__ void read_Ag(bf16x8 (&a)[4][2],
                                        const __bf16* __restrict__ abase, int t) {
#pragma unroll
    for (int f = 0; f < 4; ++f)
#pragma unroll
        for (int ks = 0; ks < 2; ++ks)
            a[f][ks] = *reinterpret_cast<const bf16x8*>(
                abase + (size_t)((MH * 4 + f) * 16) * K_TOT + t * BK + ks * 32);
}

template<int F0, int F1>
__device__ __forceinline__ void read_B(bf16x8 (&b)[4][2], const __bf16* Lbase,
                                       int brow, int gk0, int gk1) {
#pragma unroll
    for (int f = F0; f < F1; ++f) {
        const __bf16* rp = Lbase + brow + f * 16 * BK;
        b[f][0] = *reinterpret_cast<const bf16x8*>(rp + gk0);
        b[f][1] = *reinterpret_cast<const bf16x8*>(rp + gk1);
    }
}

template<int MH, int NH>
__device__ __forceinline__ void mma_quad(f32x4 (&acc)[8][4],
                                         bf16x8 (&a)[4][2], bf16x8 (&b)[4][2]) {
#pragma unroll
    for (int ks = 0; ks < 2; ++ks)
#pragma unroll
        for (int f = 0; f < 4; ++f)
#pragma unroll
            for (int j = 0; j < 2; ++j)
                acc[MH * 4 + f][NH * 2 + j] =
                    __builtin_amdgcn_mfma_f32_16x16x32_bf16(
                        a[f][ks], b[NH * 2 + j][ks],
                        acc[MH * 4 + f][NH * 2 + j], 0, 0, 0);
}

// Store one finished quadrant (4 fa x 2 fb) straight from acc.
template<int FA0, int FB0>
__device__ __forceinline__ void store_quad(const f32x4 (&acc)[8][4],
                                           float* __restrict__ C,
                                           size_t m0, size_t n0,
                                           int wr, int wc, int g2, int r15) {
#pragma unroll
    for (int fa = 0; fa < 4; ++fa)
#pragma unroll
        for (int fb = 0; fb < 2; ++fb)
#pragma unroll
            for (int q = 0; q < 4; ++q)
                C[(m0 + wr * 128 + (FA0 + fa) * 16 + g2 * 4 + q) * (size_t)N_DIM
                  + n0 + wc * 64 + (FB0 + fb) * 16 + r15]
                    = acc[FA0 + fa][FB0 + fb][q];
}

__global__ __launch_bounds__(512, 2) void GemmRS_gemm_kernel(
    const __bf16* __restrict__ Abf,   // [M][K_TOT]
    const __bf16* __restrict__ Wbf,   // [N][K_TOT]
    float* __restrict__ C)            // [M][N]
{
    __shared__ __bf16 lds[2][BN * BK];   // B double-buffer, 64 KiB

    const int tid  = threadIdx.x;
    const int lane = tid & 63;
    const int wave = tid >> 6;      // 0..7
    const int wr   = wave >> 2;     // 0..1
    const int wc   = wave & 3;      // 0..3

    // T1: XCD-aware bijective swizzle (256 blocks, 256%8==0)
    const int bid = blockIdx.x;
    const int swz = (bid & 7) * 32 + (bid >> 3);
    const int tm = swz >> 3;
    const int tn = swz & 7;
    const size_t m0 = (size_t)tm * BM;
    const size_t n0 = (size_t)tn * BN;

    const __bf16* bptr = Wbf + n0 * K_TOT;

    const int r15 = lane & 15;
    const int g2  = lane >> 4;      // 0..3
    const int l7  = lane & 7;
    const int gk0 = ((g2)     ^ l7) * 8;    // swizzled B granules
    const int gk1 = ((4 + g2) ^ l7) * 8;
    const int brow = (wc * 64 + r15) * BK;

    // per-lane A base: row = m0 + wr*128 + r15, k-granule g2*8 (no swizzle)
    const __bf16* abase = Abf + (m0 + wr * 128 + r15) * (size_t)K_TOT + g2 * 8;

    auto STB = [&](__bf16* dst, int t) {
#pragma unroll
        for (int h = 0; h < 2; ++h)
            stage_half(bptr + (size_t)(h * 128) * K_TOT + t * BK,
                       dst + h * 128 * BK, lane, wave);
    };

    f32x4 acc[8][4];
#pragma unroll
    for (int i = 0; i < 8; ++i)
#pragma unroll
        for (int j = 0; j < 4; ++j)
            acc[i][j] = (f32x4){0.f, 0.f, 0.f, 0.f};

    bf16x8 a[4][2], b[4][2];

    // ---- prologue: B tile 0 into buf0 ----
    STB(&lds[0][0], 0);
    VMCNT0();
    BAR();

    for (int t = 0; t < NT - 1; ++t) {
        __bf16* LBc = &lds[t & 1][0];
        __bf16* LBn = &lds[(t + 1) & 1][0];

        // P0: A<0> direct + b01
        read_Ag<0>(a, abase, t);
        read_B<0, 2>(b, LBc, brow, gk0, gk1);
        BAR();
        PRIO1(); mma_quad<0, 0>(acc, a, b); PRIO0();
        // P1: b23
        read_B<2, 4>(b, LBc, brow, gk0, gk1);
        BAR();
        PRIO1(); mma_quad<0, 1>(acc, a, b); PRIO0();
        // P2: A<1> direct + stage B(t+1); stage issued AFTER ga so the
        // compiler's wait for a[] leaves the 4 stage loads in flight.
        read_Ag<1>(a, abase, t);
        STB(LBn, t + 1);
        BAR();
        PRIO1(); mma_quad<1, 1>(acc, a, b); mma_quad<1, 0>(acc, a, b); PRIO0();
        VMCNT0();          // B(t+1) landed
        BAR();             // boundary: publish buf
    }

    // ---- final tile t = NT-1 (buf = (NT-1)&1), fused quadrant stores ----
    {
        const int t = NT - 1;
        __bf16* LBc = &lds[t & 1][0];
        read_Ag<0>(a, abase, t);
        read_B<0, 2>(b, LBc, brow, gk0, gk1);
        BAR();
        PRIO1(); mma_quad<0, 0>(acc, a, b); PRIO0();
        store_quad<0, 0>(acc, C, m0, n0, wr, wc, g2, r15);
        read_B<2, 4>(b, LBc, brow, gk0, gk1);
        BAR();
        PRIO1(); mma_quad<0, 1>(acc, a, b); PRIO0();
        store_quad<0, 2>(acc, C, m0, n0, wr, wc, g2, r15);
        read_Ag<1>(a, abase, t);
        BAR();
        PRIO1(); mma_quad<1, 1>(acc, a, b); PRIO0();
        store_quad<4, 2>(acc, C, m0, n0, wr, wc, g2, r15);
        PRIO1(); mma_quad<1, 0>(acc, a, b); PRIO0();
        store_quad<4, 0>(acc, C, m0, n0, wr, wc, g2, r15);
    }
}

extern "C" void kernel_launch(void* const* d_in, const int* in_sizes, int n_in,
                              void* d_out, int out_size, void* d_ws, size_t ws_size,
                              hipStream_t stream) {
    (void)in_sizes; (void)n_in; (void)out_size; (void)ws_size;
    const float* A = (const float*)d_in[0];   // [8][8192][256] fp32
    const float* W = (const float*)d_in[1];   // [8][2048][256] fp32
    float* C = (float*)d_out;                 // [8192][2048] fp32

    __bf16* Abf = (__bf16*)d_ws;                                      // 32 MiB
    __bf16* Wbf = (__bf16*)((char*)d_ws + (size_t)M_DIM * K_TOT * 2); // + 8 MiB

    GemmRS_convert_kernel<<<2048, 256, 0, stream>>>(A, W, Abf, Wbf);
    GemmRS_gemm_kernel<<<(M_DIM / BM) * (N_DIM / BN), 512, 0, stream>>>(Abf, Wbf, C);
}

// Round 11
// 78.171 us; speedup vs baseline: 2.3715x; 2.3715x over previous
//
#include <hip/hip_runtime.h>
#include <hip/hip_bf16.h>

typedef __bf16 bf16x8 __attribute__((ext_vector_type(8)));
typedef __bf16 bf16x4 __attribute__((ext_vector_type(4)));
typedef float f32x4 __attribute__((ext_vector_type(4)));

#define WORLD 8
#define M_DIM 8192
#define N_DIM 2048
#define KL 256
#define K_TOT 2048

#define BM 256
#define BN 256
#define BK 64
#define NT (K_TOT / BK)   // 32 K-tiles
#define NITER (NT / 2)    // 16 iterations, 2 tiles each

#define AS1 __attribute__((address_space(1)))
#define AS3 __attribute__((address_space(3)))

#define BAR()    __builtin_amdgcn_s_barrier()
#define VMCNT4() asm volatile("s_waitcnt vmcnt(4)" ::: "memory")
#define VMCNT0() asm volatile("s_waitcnt vmcnt(0)" ::: "memory")
#define PRIO1()  __builtin_amdgcn_s_setprio(1)
#define PRIO0()  __builtin_amdgcn_s_setprio(0)

// ---------------------------------------------------------------------------
// Pass 1: fp32 -> bf16 conversion + rank-dim gather (unchanged).
// ---------------------------------------------------------------------------
__global__ __launch_bounds__(256) void GemmRS_convert_kernel(
    const float* __restrict__ A,
    const float* __restrict__ W,
    __bf16* __restrict__ Abf,
    __bf16* __restrict__ Wbf)
{
    const long long GA = (long long)WORLD * M_DIM * KL / 4;
    const long long GW = (long long)WORLD * N_DIM * KL / 4;
    const long long stride = (long long)gridDim.x * blockDim.x;
    for (long long g = (long long)blockIdx.x * blockDim.x + threadIdx.x;
         g < GA + GW; g += stride) {
        if (g < GA) {
            const long long e = g * 4;
            const int k = (int)(e & (KL - 1));
            const int m = (int)((e >> 8) & (M_DIM - 1));
            const int r = (int)(e >> 21);
            const float4 v = *reinterpret_cast<const float4*>(A + e);
            bf16x4 o;
            o[0] = (__bf16)v.x; o[1] = (__bf16)v.y;
            o[2] = (__bf16)v.z; o[3] = (__bf16)v.w;
            *reinterpret_cast<bf16x4*>(Abf + (size_t)m * K_TOT + r * KL + k) = o;
        } else {
            const long long e = (g - GA) * 4;
            const int k = (int)(e & (KL - 1));
            const int n = (int)((e >> 8) & (N_DIM - 1));
            const int r = (int)(e >> 19);
            const float4 v = *reinterpret_cast<const float4*>(W + e);
            bf16x4 o;
            o[0] = (__bf16)v.x; o[1] = (__bf16)v.y;
            o[2] = (__bf16)v.z; o[3] = (__bf16)v.w;
            *reinterpret_cast<bf16x4*>(Wbf + (size_t)n * K_TOT + r * KL + k) = o;
        }
    }
}

// ---------------------------------------------------------------------------
// Pass 2 (R11): R8 structure with barrier schedule thinned 10 -> 6 per iter.
// Kept BARs: P1, P2, P5, P6 (each guards the NEXT phase's LDS overwrite)
// plus the two tile-boundary BARs (merged with P3/P7's, publish staging).
// Dropped: P0/P4 pre-mma BARs (their stages target regions whose reads all
// retired before the preceding boundary BAR) and P3/P7's pre-mma BARs
// (P2/P6's collective BAR already implies all waves drained their b-reads,
// because each wave's path there passes through its own mma+lgkm).
// ---------------------------------------------------------------------------

__device__ __forceinline__ void stage_half(const __bf16* srcbase, __bf16* dstbase,
                                           int lane, int wave) {
    const int rl = lane >> 3;
    const int g  = (lane & 7) ^ rl;           // swizzle on GLOBAL source
    const __bf16* s = srcbase + (size_t)(wave * 8 + rl) * K_TOT + g * 8;
#pragma unroll
    for (int j = 0; j < 2; ++j) {
        __builtin_amdgcn_global_load_lds(
            (const AS1 void*)(s + (size_t)(j * 64) * K_TOT),
            (AS3 void*)(dstbase + (j * 64 + wave * 8) * BK),
            16, 0, 0);
    }
}

template<int MH>
__device__ __forceinline__ void read_A(bf16x8 (&a)[4][2], const __bf16* Lbase,
                                       int arow, int gk0, int gk1) {
#pragma unroll
    for (int f = 0; f < 4; ++f) {
        const __bf16* rp = Lbase + arow + (MH * 4 + f) * 16 * BK;
        a[f][0] = *reinterpret_cast<const bf16x8*>(rp + gk0);
        a[f][1] = *reinterpret_cast<const bf16x8*>(rp + gk1);
    }
}

template<int F0, int F1>
__device__ __forceinline__ void read_B(bf16x8 (&b)[4][2], const __bf16* Lbase,
                                       int brow, int gk0, int gk1) {
#pragma unroll
    for (int f = F0; f < F1; ++f) {
        const __bf16* rp = Lbase + brow + f * 16 * BK;
        b[f][0] = *reinterpret_cast<const bf16x8*>(rp + gk0);
        b[f][1] = *reinterpret_cast<const bf16x8*>(rp + gk1);
    }
}

// k-outer: 8 independent accumulator chains between dependent reuses.
template<int MH, int NH>
__device__ __forceinline__ void mma_quad(f32x4 (&acc)[8][4],
                                         bf16x8 (&a)[4][2], bf16x8 (&b)[4][2]) {
#pragma unroll
    for (int ks = 0; ks < 2; ++ks)
#pragma unroll
        for (int f = 0; f < 4; ++f)
#pragma unroll
            for (int j = 0; j < 2; ++j)
                acc[MH * 4 + f][NH * 2 + j] =
                    __builtin_amdgcn_mfma_f32_16x16x32_bf16(
                        a[f][ks], b[NH * 2 + j][ks],
                        acc[MH * 4 + f][NH * 2 + j], 0, 0, 0);
}

// Store one finished quadrant (4 fa x 2 fb) straight from acc.
template<int FA0, int FB0>
__device__ __forceinline__ void store_quad(const f32x4 (&acc)[8][4],
                                           float* __restrict__ C,
                                           size_t m0, size_t n0,
                                           int wr, int wc, int g2, int r15) {
#pragma unroll
    for (int fa = 0; fa < 4; ++fa)
#pragma unroll
        for (int fb = 0; fb < 2; ++fb)
#pragma unroll
            for (int q = 0; q < 4; ++q)
                C[(m0 + wr * 128 + (FA0 + fa) * 16 + g2 * 4 + q) * (size_t)N_DIM
                  + n0 + wc * 64 + (FB0 + fb) * 16 + r15]
                    = acc[FA0 + fa][FB0 + fb][q];
}

__global__ __launch_bounds__(512, 2) void GemmRS_gemm_kernel(
    const __bf16* __restrict__ Abf,   // [M][K_TOT]
    const __bf16* __restrict__ Wbf,   // [N][K_TOT]
    float* __restrict__ C)            // [M][N]
{
    __shared__ __bf16 lds[2][2][BM * BK];   // 128 KiB

    const int tid  = threadIdx.x;
    const int lane = tid & 63;
    const int wave = tid >> 6;      // 0..7
    const int wr   = wave >> 2;     // 0..1
    const int wc   = wave & 3;      // 0..3

    // T1: XCD-aware bijective swizzle (256 blocks, 256%8==0)
    const int bid = blockIdx.x;
    const int swz = (bid & 7) * 32 + (bid >> 3);
    const int tm = swz >> 3;
    const int tn = swz & 7;
    const size_t m0 = (size_t)tm * BM;
    const size_t n0 = (size_t)tn * BN;

    const __bf16* aptr = Abf + m0 * K_TOT;
    const __bf16* bptr = Wbf + n0 * K_TOT;

    __bf16* LA0 = &lds[0][0][0];
    __bf16* LB0 = &lds[0][1][0];
    __bf16* LA1 = &lds[1][0][0];
    __bf16* LB1 = &lds[1][1][0];

    auto ST = [&](__bf16* dst, const __bf16* srcp, int h, int t) {
        stage_half(srcp + (size_t)(h * 128) * K_TOT + t * BK,
                   dst + h * 128 * BK, lane, wave);
    };

    const int r15 = lane & 15;
    const int g2  = lane >> 4;      // 0..3
    const int l7  = lane & 7;
    const int gk0 = ((g2)     ^ l7) * 8;
    const int gk1 = ((4 + g2) ^ l7) * 8;
    const int arow = (wr * 128 + r15) * BK;
    const int brow = (wc * 64  + r15) * BK;

    f32x4 acc[8][4];
#pragma unroll
    for (int i = 0; i < 8; ++i)
#pragma unroll
        for (int j = 0; j < 4; ++j)
            acc[i][j] = (f32x4){0.f, 0.f, 0.f, 0.f};

    bf16x8 a[4][2], b[4][2];

    // ---- prologue: buf0 <- tile0 (A+B), buf1.B <- tile1 ----
    ST(LA0, aptr, 0, 0);
    ST(LA0, aptr, 1, 0);
    ST(LB0, bptr, 0, 0);
    ST(LB0, bptr, 1, 0);
    ST(LB1, bptr, 0, 1);
    ST(LB1, bptr, 1, 1);
    VMCNT4();
    BAR();

    for (int i = 0; i < NITER - 1; ++i) {
        const int t1 = 2 * i + 1;
        const int t2 = 2 * i + 2;
        const int t3 = (2 * i + 3 < NT) ? 2 * i + 3 : NT - 1;

        // ========== tile-group 0: consume buf0 (tile 2i) ==========
        // P0 (no BAR: LA1 reads retired before boundary BAR)
        read_A<0>(a, LA0, arow, gk0, gk1);
        read_B<0, 2>(b, LB0, brow, gk0, gk1);
        ST(LA1, aptr, 0, t1);
        PRIO1(); mma_quad<0, 0>(acc, a, b); PRIO0();
        // P1 (BAR guards P2's LB0 overwrite)
        read_B<2, 4>(b, LB0, brow, gk0, gk1);
        ST(LA1, aptr, 1, t1);
        BAR();
        PRIO1(); mma_quad<0, 1>(acc, a, b); PRIO0();
        // P2 (BAR guards P3's LB0h1 overwrite; also implies all b-reads drained)
        read_A<1>(a, LA0, arow, gk0, gk1);
        ST(LB0, bptr, 0, t2);
        BAR();
        PRIO1(); mma_quad<1, 1>(acc, a, b); PRIO0();
        // P3 (merged: single boundary BAR after vmcnt)
        ST(LB0, bptr, 1, t2);
        PRIO1(); mma_quad<1, 0>(acc, a, b); PRIO0();
        VMCNT4();
        BAR();   // boundary: publish buf1 staging

        // ========== tile-group 1: consume buf1 (tile 2i+1) ==========
        // P4 (no BAR)
        read_A<0>(a, LA1, arow, gk0, gk1);
        read_B<0, 2>(b, LB1, brow, gk0, gk1);
        ST(LA0, aptr, 0, t2);
        PRIO1(); mma_quad<0, 0>(acc, a, b); PRIO0();
        // P5
        read_B<2, 4>(b, LB1, brow, gk0, gk1);
        ST(LA0, aptr, 1, t2);
        BAR();
        PRIO1(); mma_quad<0, 1>(acc, a, b); PRIO0();
        // P6
        read_A<1>(a, LA1, arow, gk0, gk1);
        ST(LB1, bptr, 0, t3);
        BAR();
        PRIO1(); mma_quad<1, 1>(acc, a, b); PRIO0();
        // P7 (merged)
        ST(LB1, bptr, 1, t3);
        PRIO1(); mma_quad<1, 0>(acc, a, b); PRIO0();
        VMCNT4();
        BAR();   // boundary: publish buf0 staging
    }

    // ========== FINAL iteration: tiles NT-2 (buf0) and NT-1 (buf1) ==========
    // Entering: outstanding vmem = 4 (LB1 h0/h1 of tile NT-1).
    {
        const int t1 = NT - 1;
        // P0 (no BAR; stages LA1 — safe per boundary BAR)
        read_A<0>(a, LA0, arow, gk0, gk1);
        read_B<0, 2>(b, LB0, brow, gk0, gk1);
        ST(LA1, aptr, 0, t1);
        PRIO1(); mma_quad<0, 0>(acc, a, b); PRIO0();
        // P1 (no further stages into LB0 this iter -> BAR droppable too)
        read_B<2, 4>(b, LB0, brow, gk0, gk1);
        ST(LA1, aptr, 1, t1);
        PRIO1(); mma_quad<0, 1>(acc, a, b); PRIO0();
        // P2 (no stage)
        read_A<1>(a, LA0, arow, gk0, gk1);
        PRIO1(); mma_quad<1, 1>(acc, a, b); PRIO0();
        // P3 (no stage)
        PRIO1(); mma_quad<1, 0>(acc, a, b); PRIO0();
        VMCNT0();          // drain LA1 (4) + carried LB1 (4)
        BAR();             // publish buf1

        // P4..P7: no stages, no cross-wave hazards -> no BARs; stores overlap
        read_A<0>(a, LA1, arow, gk0, gk1);
        read_B<0, 2>(b, LB1, brow, gk0, gk1);
        PRIO1(); mma_quad<0, 0>(acc, a, b); PRIO0();
        store_quad<0, 0>(acc, C, m0, n0, wr, wc, g2, r15);
        read_B<2, 4>(b, LB1, brow, gk0, gk1);
        PRIO1(); mma_quad<0, 1>(acc, a, b); PRIO0();
        store_quad<0, 2>(acc, C, m0, n0, wr, wc, g2, r15);
        read_A<1>(a, LA1, arow, gk0, gk1);
        PRIO1(); mma_quad<1, 1>(acc, a, b); PRIO0();
        store_quad<4, 2>(acc, C, m0, n0, wr, wc, g2, r15);
        PRIO1(); mma_quad<1, 0>(acc, a, b); PRIO0();
        store_quad<4, 0>(acc, C, m0, n0, wr, wc, g2, r15);
    }
}

extern "C" void kernel_launch(void* const* d_in, const int* in_sizes, int n_in,
                              void* d_out, int out_size, void* d_ws, size_t ws_size,
                              hipStream_t stream) {
    (void)in_sizes; (void)n_in; (void)out_size; (void)ws_size;
    const float* A = (const float*)d_in[0];   // [8][8192][256] fp32
    const float* W = (const float*)d_in[1];   // [8][2048][256] fp32
    float* C = (float*)d_out;                 // [8192][2048] fp32

    __bf16* Abf = (__bf16*)d_ws;                                      // 32 MiB
    __bf16* Wbf = (__bf16*)((char*)d_ws + (size_t)M_DIM * K_TOT * 2); // + 8 MiB

    GemmRS_convert_kernel<<<2048, 256, 0, stream>>>(A, W, Abf, Wbf);
    GemmRS_gemm_kernel<<<(M_DIM / BM) * (N_DIM / BN), 512, 0, stream>>>(Abf, Wbf, C);
}